// Round 2
// baseline (588.142 us; speedup 1.0000x reference)
//
#include <hip/hip_runtime.h>
#include <hip/hip_bf16.h>
#include <stdint.h>

// Problem constants (from reference)
#define H   128
#define NM  5000
#define NO  100000
#define EA  1000000
#define EC  500000
#define ET  1000000
#define EL  500000

typedef __hip_bfloat16 bf16;

// ---- dtype-flexible load: flag-selected fp32 vs bf16 ----
template<bool ISF32>
__device__ __forceinline__ float ldf(const void* p, int i) {
    if constexpr (ISF32) return ((const float*)p)[i];
    else                 return __bfloat162float(((const bf16*)p)[i]);
}

// ---- bf16 pair decode helpers (pair packed in a uint32, little-endian) ----
__device__ __forceinline__ float bflo(uint32_t v) {
    union { uint32_t u; float f; } c; c.u = v << 16; return c.f;
}
__device__ __forceinline__ float bfhi(uint32_t v) {
    union { uint32_t u; float f; } c; c.u = v & 0xFFFF0000u; return c.f;
}

// ---- zero the count/sum/flag scratch region ----
__global__ void zero_kernel(int* __restrict__ p, int n) {
    int i = blockIdx.x * blockDim.x + threadIdx.x;
    if (i < n) p[i] = 0;
}

// ---- dtype probe: fp32 data viewed as u16 contains exponent-0xFF patterns ----
__global__ void detect_kernel(const uint16_t* __restrict__ x, int n, int* __restrict__ flag) {
    int i = blockIdx.x * blockDim.x + threadIdx.x;
    if (i < n) {
        if (((x[i] >> 7) & 0xFF) == 0xFF) atomicOr(flag, 1);
    }
}

// ---- node encoder: h = x @ W + b (store bf16), fused column-sum ----
template<int FIN, bool ISF32>
__device__ __forceinline__ void encode_body(
    const void* __restrict__ x, const void* __restrict__ W,
    const void* __restrict__ b, bf16* __restrict__ h,
    float* __restrict__ sum_out, int N)
{
    const int c = threadIdx.x & 127;
    const int u = threadIdx.x >> 7;
    float wcol[FIN];
#pragma unroll
    for (int k = 0; k < FIN; ++k) wcol[k] = ldf<ISF32>(W, k * H + c);
    const float bc = ldf<ISF32>(b, c);
    float s = 0.f;
    const int stride = gridDim.x * 2;
    for (int n = blockIdx.x * 2 + u; n < N; n += stride) {
        float acc = bc;
#pragma unroll
        for (int k = 0; k < FIN; ++k)
            acc += ldf<ISF32>(x, n * FIN + k) * wcol[k];
        h[n * H + c] = __float2bfloat16(acc);
        s += acc;
    }
    __shared__ float red[256];
    red[threadIdx.x] = s;
    __syncthreads();
    if (threadIdx.x < 128) {
        float t = red[threadIdx.x] + red[threadIdx.x + 128];
        atomicAdd(&sum_out[(blockIdx.x & 7) * H + threadIdx.x], t);
    }
}

template<int FIN>
__global__ __launch_bounds__(256) void encode_kernel(
    const void* x, const void* W, const void* b, bf16* h,
    float* sum_out, int N, const int* __restrict__ flag)
{
    if (*flag) encode_body<FIN, true >(x, W, b, h, sum_out, N);
    else       encode_body<FIN, false>(x, W, b, h, sum_out, N);
}

// ---- degree counts ----
__global__ __launch_bounds__(256) void count_kernel(
    const int* __restrict__ dst, int* __restrict__ cnt, int E)
{
    const int stride = gridDim.x * blockDim.x;
    for (int i = blockIdx.x * blockDim.x + threadIdx.x; i < E; i += stride)
        atomicAdd(&cnt[dst[i]], 1);
}

// ---- GINE edge sum: out += sum_e relu(h_src[src_e] + ea_e @ We + be) ----
// wave-per-edge: lane l owns channels {2l, 2l+1}. h is internal bf16 always.
template<int ED, bool ISF32>
__device__ __forceinline__ void gine_body(
    const bf16* __restrict__ hsrc, const int* __restrict__ src,
    const void* __restrict__ ea, const void* __restrict__ We,
    const void* __restrict__ be, float* __restrict__ sum_out, int E)
{
    const int lane = threadIdx.x & 63;
    const int gw = blockIdx.x * (blockDim.x >> 6) + (threadIdx.x >> 6);
    const int nw = gridDim.x * (blockDim.x >> 6);
    const uint32_t* __restrict__ h32 = (const uint32_t*)hsrc;
    float w0[ED], w1[ED];
#pragma unroll
    for (int k = 0; k < ED; ++k) {
        w0[k] = ldf<ISF32>(We, k * H + 2 * lane);
        w1[k] = ldf<ISF32>(We, k * H + 2 * lane + 1);
    }
    const float b0 = ldf<ISF32>(be, 2 * lane);
    const float b1 = ldf<ISF32>(be, 2 * lane + 1);
    float acc0 = 0.f, acc1 = 0.f;
    for (int e = gw; e < E; e += nw) {
        const int sidx = src[e];
        const uint32_t hv = h32[sidx * 64 + lane];
        float e0 = b0, e1 = b1;
#pragma unroll
        for (int k = 0; k < ED; ++k) {
            const float a = ldf<ISF32>(ea, e * ED + k);
            e0 = fmaf(a, w0[k], e0);
            e1 = fmaf(a, w1[k], e1);
        }
        acc0 += fmaxf(bflo(hv) + e0, 0.f);
        acc1 += fmaxf(bfhi(hv) + e1, 0.f);
    }
    __shared__ float red0[256], red1[256];
    red0[threadIdx.x] = acc0; red1[threadIdx.x] = acc1;
    __syncthreads();
    if (threadIdx.x < 64) {
        const int l = threadIdx.x;
        float r0 = red0[l] + red0[l + 64] + red0[l + 128] + red0[l + 192];
        float r1 = red1[l] + red1[l + 64] + red1[l + 128] + red1[l + 192];
        float* d = &sum_out[(blockIdx.x & 7) * H + 2 * l];
        atomicAdd(d, r0);
        atomicAdd(d + 1, r1);
    }
}

template<int ED>
__global__ __launch_bounds__(256) void gine_kernel(
    const bf16* hsrc, const int* src, const void* ea, const void* We,
    const void* be, float* sum_out, int E, const int* __restrict__ flag)
{
    if (*flag) gine_body<ED, true >(hsrc, src, ea, We, be, sum_out, E);
    else       gine_body<ED, false>(hsrc, src, ea, We, be, sum_out, E);
}

// ---- SAGE edge sum: out += sum_e h_src[src_e] / cnt[dst_e] (no dtype deps) ----
__global__ __launch_bounds__(256) void sage_kernel(
    const bf16* __restrict__ hsrc, const int* __restrict__ src,
    const int* __restrict__ dst, const int* __restrict__ cnt,
    float* __restrict__ sum_out, int E)
{
    const int lane = threadIdx.x & 63;
    const int gw = blockIdx.x * (blockDim.x >> 6) + (threadIdx.x >> 6);
    const int nw = gridDim.x * (blockDim.x >> 6);
    const uint32_t* __restrict__ h32 = (const uint32_t*)hsrc;
    float acc0 = 0.f, acc1 = 0.f;
    for (int e = gw; e < E; e += nw) {
        const int sidx = src[e];
        const int didx = dst[e];
        const float w = 1.0f / (float)cnt[didx];  // cnt >= 1 for any dst that appears
        const uint32_t hv = h32[sidx * 64 + lane];
        acc0 = fmaf(w, bflo(hv), acc0);
        acc1 = fmaf(w, bfhi(hv), acc1);
    }
    __shared__ float red0[256], red1[256];
    red0[threadIdx.x] = acc0; red1[threadIdx.x] = acc1;
    __syncthreads();
    if (threadIdx.x < 64) {
        const int l = threadIdx.x;
        float r0 = red0[l] + red0[l + 64] + red0[l + 128] + red0[l + 192];
        float r1 = red1[l] + red1[l + 64] + red1[l + 128] + red1[l + 192];
        float* d = &sum_out[(blockIdx.x & 7) * H + 2 * l];
        atomicAdd(d, r0);
        atomicAdd(d + 1, r1);
    }
}

// ---- final: reduce 8 copies, five 128x128 mat-vecs, write 256 outputs ----
// sums layout (floats): [0]=HM, [1024]=HO, [2048]=A, [3072]=C, [4096]=TV, [5120]=LOG
template<bool ISF32>
__device__ __forceinline__ void final_body(
    const float* __restrict__ S,
    const void* Wn_a, const void* bn_a, const void* Wn_c, const void* bn_c,
    const void* Wl_tv, const void* bl_tv, const void* Wr_tv,
    const void* Wl_log, const void* bl_log, const void* Wr_log,
    void* __restrict__ out)
{
    __shared__ float vtv[H], vmhm[H], va[H], vc[H], vlog[H], vmho[H];
    const int t = threadIdx.x;
    if (t < H) {
        float shm = 0.f, sho = 0.f, sa = 0.f, sc = 0.f, stv = 0.f, sl = 0.f;
#pragma unroll
        for (int cp = 0; cp < 8; ++cp) {
            shm += S[cp * H + t];
            sho += S[1024 + cp * H + t];
            sa  += S[2048 + cp * H + t];
            sc  += S[3072 + cp * H + t];
            stv += S[4096 + cp * H + t];
            sl  += S[5120 + cp * H + t];
        }
        const float mhm = shm * (1.f / NM);
        const float mho = sho * (1.f / NO);
        vmhm[t] = mhm;
        vmho[t] = mho;
        va[t]  = sa * (1.f / NO) + mho;
        vc[t]  = sc * (1.f / NO) + mho;
        vtv[t] = stv * (1.f / NM);
        vlog[t] = sl * (1.f / NO);
    }
    __syncthreads();
    float res; int oidx;
    if (t < H) {
        // g_m = mean_agg_tv @ Wl_tv + bl_tv + mean_h_m @ Wr_tv
        float acc = ldf<ISF32>(bl_tv, t);
        for (int k = 0; k < H; ++k) {
            acc = fmaf(vtv[k],  ldf<ISF32>(Wl_tv, k * H + t), acc);
            acc = fmaf(vmhm[k], ldf<ISF32>(Wr_tv, k * H + t), acc);
        }
        res = acc; oidx = t;
    } else {
        const int c = t - H;
        // g_o = (o_a + o_c + o_log)/3, each collapsed to a mat-vec
        float acc = ldf<ISF32>(bn_a, c) + ldf<ISF32>(bn_c, c) + ldf<ISF32>(bl_log, c);
        for (int k = 0; k < H; ++k) {
            acc = fmaf(va[k],   ldf<ISF32>(Wn_a, k * H + c), acc);
            acc = fmaf(vc[k],   ldf<ISF32>(Wn_c, k * H + c), acc);
            acc = fmaf(vlog[k], ldf<ISF32>(Wl_log, k * H + c), acc);
            acc = fmaf(vmho[k], ldf<ISF32>(Wr_log, k * H + c), acc);
        }
        res = acc * (1.f / 3.f); oidx = H + c;
    }
    if constexpr (ISF32) ((float*)out)[oidx] = res;
    else                 ((bf16*)out)[oidx] = __float2bfloat16(res);
}

__global__ __launch_bounds__(256) void final_kernel(
    const float* S,
    const void* Wn_a, const void* bn_a, const void* Wn_c, const void* bn_c,
    const void* Wl_tv, const void* bl_tv, const void* Wr_tv,
    const void* Wl_log, const void* bl_log, const void* Wr_log,
    void* out, const int* __restrict__ flag)
{
    if (*flag) final_body<true >(S, Wn_a, bn_a, Wn_c, bn_c, Wl_tv, bl_tv, Wr_tv, Wl_log, bl_log, Wr_log, out);
    else       final_body<false>(S, Wn_a, bn_a, Wn_c, bn_c, Wl_tv, bl_tv, Wr_tv, Wl_log, bl_log, Wr_log, out);
}

extern "C" void kernel_launch(void* const* d_in, const int* in_sizes, int n_in,
                              void* d_out, int out_size, void* d_ws, size_t ws_size,
                              hipStream_t stream) {
    // Inputs in setup_inputs() dict order
    const void* x_m      = d_in[0];
    const void* x_o      = d_in[1];
    const void* ea_a     = d_in[2];
    const void* ea_c     = d_in[3];
    const int*  ei_a     = (const int*)d_in[4];   // [2, EA]: rows src, dst
    const int*  ei_c     = (const int*)d_in[5];
    const int*  ei_tv    = (const int*)d_in[6];
    const int*  ei_log   = (const int*)d_in[7];
    const void* Wm       = d_in[8];
    const void* bm       = d_in[9];
    const void* Wo       = d_in[10];
    const void* bo       = d_in[11];
    const void* Wn_a     = d_in[12];
    const void* bn_a     = d_in[13];
    const void* We_a     = d_in[14];
    const void* be_a     = d_in[15];
    const void* Wn_c     = d_in[16];
    const void* bn_c     = d_in[17];
    const void* We_c     = d_in[18];
    const void* be_c     = d_in[19];
    const void* Wl_tv    = d_in[20];
    const void* bl_tv    = d_in[21];
    const void* Wr_tv    = d_in[22];
    const void* Wl_log   = d_in[23];
    const void* bl_log   = d_in[24];
    const void* Wr_log   = d_in[25];

    // Workspace layout (bytes):
    //   [0, 1.28M)        h_m  bf16 [NM, H]
    //   [1.28M, 26.88M)   h_o  bf16 [NO, H]
    //   [26.88M, ...)     cnt_m int[NM], cnt_o int[NO], sums 6*8*128 fp32, flag
    char* ws = (char*)d_ws;
    bf16*  h_m   = (bf16*)(ws);
    bf16*  h_o   = (bf16*)(ws + 1280000);
    int*   cnt_m = (int*)(ws + 26880000);
    int*   cnt_o = (int*)(ws + 26900000);
    float* sums  = (float*)(ws + 27300000);
    int*   flag  = (int*)(ws + 27324576);
    float* S_HM  = sums;
    float* S_HO  = sums + 1024;
    float* S_A   = sums + 2048;
    float* S_C   = sums + 3072;
    float* S_TV  = sums + 4096;
    float* S_LOG = sums + 5120;

    // zero counts + sums + flag (contiguous from 26880000): 444580 bytes
    const int nzero = 111145;
    zero_kernel<<<(nzero + 255) / 256, 256, 0, stream>>>((int*)(ws + 26880000), nzero);

    // dtype probe on x_machine (15000 elements; safe as u16 under either dtype)
    detect_kernel<<<(15000 + 255) / 256, 256, 0, stream>>>((const uint16_t*)x_m, 15000, flag);

    // encoders (fused column-sums)
    encode_kernel<3><<<640, 256, 0, stream>>>(x_m, Wm, bm, h_m, S_HM, NM, flag);
    encode_kernel<4><<<1024, 256, 0, stream>>>(x_o, Wo, bo, h_o, S_HO, NO, flag);

    // degree counts for SAGE mean
    count_kernel<<<512, 256, 0, stream>>>(ei_tv + ET, cnt_m, ET);
    count_kernel<<<512, 256, 0, stream>>>(ei_log + EL, cnt_o, EL);

    // edge sums
    gine_kernel<3><<<2048, 256, 0, stream>>>(h_m, ei_a, ea_a, We_a, be_a, S_A, EA, flag);
    gine_kernel<1><<<1024, 256, 0, stream>>>(h_o, ei_c, ea_c, We_c, be_c, S_C, EC, flag);
    sage_kernel<<<2048, 256, 0, stream>>>(h_o, ei_tv, ei_tv + ET, cnt_m, S_TV, ET);
    sage_kernel<<<1024, 256, 0, stream>>>(h_o, ei_log, ei_log + EL, cnt_o, S_LOG, EL);

    // final mat-vecs + output
    final_kernel<<<1, 256, 0, stream>>>(sums,
        Wn_a, bn_a, Wn_c, bn_c, Wl_tv, bl_tv, Wr_tv, Wl_log, bl_log, Wr_log,
        d_out, flag);
}

// Round 3
// 456.867 us; speedup vs baseline: 1.2873x; 1.2873x over previous
//
#include <hip/hip_runtime.h>
#include <hip/hip_bf16.h>
#include <stdint.h>

// Problem constants (from reference)
#define H   128
#define NM  5000
#define NO  100000
#define EA  1000000
#define EC  500000
#define ET  1000000
#define EL  500000

typedef __hip_bfloat16 bf16;

// sums layout (float offsets)
#define SA_OFF 0      // 8 copies x 128 : sum_e relu(...) for assign
#define SC_OFF 1024   // 8 copies x 128 : same for completion
#define XM_OFF 2048   // 8 copies x 4   : sum over nodes of x_m components
#define XO_OFF 2080   // 8 copies x 4   : sum over nodes of x_o components
#define TV_OFF 2112   // 8 copies x 8   : [0..3]=sum w*x_o, [4]=sum w   (type_valid)
#define LG_OFF 2176   // 8 copies x 8   : same for logical
#define SUMS_FLOATS 2240

// phase1 block partition
#define B_GA 1536
#define B_GC 640
#define B_CT 256
#define B_CL 128
#define B_MM 8
#define B_MO 32
#define P1_BLOCKS (B_GA + B_GC + B_CT + B_CL + B_MM + B_MO)

struct Par {
    const void *x_m, *x_o, *ea_a, *ea_c;
    const int *ei_a, *ei_c, *ei_tv, *ei_log;
    const void *Wm, *bm, *Wo, *bo;
    const void *Wn_a, *bn_a, *We_a, *be_a;
    const void *Wn_c, *bn_c, *We_c, *be_c;
    const void *Wl_tv, *bl_tv, *Wr_tv, *Wl_log, *bl_log, *Wr_log;
    float *w_tv, *w_log;
    int *cnt_m, *cnt_o;
    float *sums;
    const int *flag;
    void *out;
};

// ---- dtype-flexible load: flag-selected fp32 vs bf16 ----
template<bool ISF32>
__device__ __forceinline__ float ldf(const void* p, int i) {
    if constexpr (ISF32) return ((const float*)p)[i];
    else                 return __bfloat162float(((const bf16*)p)[i]);
}

__device__ __forceinline__ float wred(float v) {
#pragma unroll
    for (int o = 32; o; o >>= 1) v += __shfl_down(v, o, 64);
    return v;
}

// ---- zero scratch ----
__global__ void zero_kernel(int* __restrict__ p, int n) {
    int i = blockIdx.x * blockDim.x + threadIdx.x;
    if (i < n) p[i] = 0;
}

// ---- dtype probe: fp32 viewed as u16 contains exponent-0xFF patterns ----
__global__ void detect_kernel(const uint16_t* __restrict__ x, int n, int* __restrict__ flag) {
    int i = blockIdx.x * blockDim.x + threadIdx.x;
    if (i < n) {
        if (((x[i] >> 7) & 0xFF) == 0xFF) atomicOr(flag, 1);
    }
}

// ---- GINE edge sum, h recomputed from x on the fly ----
// Sout += sum_e relu(x[src_e]@Wx + bx + ea_e@We + be), per-channel.
// lane owns channels {2l, 2l+1}; contiguous edge chunk per wave.
template<int ED, int FIN, bool ISF32>
__device__ __forceinline__ void gine_body(
    const int* __restrict__ src, const void* __restrict__ ea,
    const void* __restrict__ x, const void* __restrict__ We,
    const void* __restrict__ be, const void* __restrict__ Wx,
    const void* __restrict__ bx, float* __restrict__ Sout,
    int E, int relblk, int nblk)
{
    const int lane = threadIdx.x & 63;
    const int c0 = 2 * lane, c1 = c0 + 1;
    float we0[ED], we1[ED], wx0[FIN], wx1[FIN];
#pragma unroll
    for (int k = 0; k < ED; ++k) {
        we0[k] = ldf<ISF32>(We, k * H + c0);
        we1[k] = ldf<ISF32>(We, k * H + c1);
    }
#pragma unroll
    for (int k = 0; k < FIN; ++k) {
        wx0[k] = ldf<ISF32>(Wx, k * H + c0);
        wx1[k] = ldf<ISF32>(Wx, k * H + c1);
    }
    const float b0 = ldf<ISF32>(be, c0) + ldf<ISF32>(bx, c0);
    const float b1 = ldf<ISF32>(be, c1) + ldf<ISF32>(bx, c1);

    const int wv = relblk * 4 + (threadIdx.x >> 6);
    const int nw = nblk * 4;
    const int chunk = (E + nw - 1) / nw;
    int e0 = wv * chunk;
    int e1 = e0 + chunk; if (e1 > E) e1 = E; if (e0 > E) e0 = E;

    float acc0 = 0.f, acc1 = 0.f;
#pragma unroll 2
    for (int e = e0; e < e1; ++e) {
        const int s = src[e];
        float m0 = b0, m1 = b1;
        if constexpr (FIN == 4 && ISF32) {
            const float4 xv = ((const float4*)x)[s];
            m0 = fmaf(xv.x, wx0[0], m0); m1 = fmaf(xv.x, wx1[0], m1);
            m0 = fmaf(xv.y, wx0[1], m0); m1 = fmaf(xv.y, wx1[1], m1);
            m0 = fmaf(xv.z, wx0[2], m0); m1 = fmaf(xv.z, wx1[2], m1);
            m0 = fmaf(xv.w, wx0[3], m0); m1 = fmaf(xv.w, wx1[3], m1);
        } else {
#pragma unroll
            for (int k = 0; k < FIN; ++k) {
                const float xk = ldf<ISF32>(x, s * FIN + k);
                m0 = fmaf(xk, wx0[k], m0);
                m1 = fmaf(xk, wx1[k], m1);
            }
        }
#pragma unroll
        for (int k = 0; k < ED; ++k) {
            const float a = ldf<ISF32>(ea, e * ED + k);
            m0 = fmaf(a, we0[k], m0);
            m1 = fmaf(a, we1[k], m1);
        }
        acc0 += fmaxf(m0, 0.f);
        acc1 += fmaxf(m1, 0.f);
    }
    __shared__ float r0[256], r1[256];
    r0[threadIdx.x] = acc0; r1[threadIdx.x] = acc1;
    __syncthreads();
    if (threadIdx.x < 64) {
        const int l = threadIdx.x;
        float s0 = r0[l] + r0[l + 64] + r0[l + 128] + r0[l + 192];
        float s1 = r1[l] + r1[l + 64] + r1[l + 128] + r1[l + 192];
        float* d = &Sout[(blockIdx.x & 7) * H + 2 * l];
        atomicAdd(d, s0);
        atomicAdd(d + 1, s1);
    }
}

// ---- degree counts (contiguous) ----
__device__ __forceinline__ void count_body(
    const int* __restrict__ dst, int* __restrict__ cnt, int E, int relblk, int nblk)
{
    const int stride = nblk * 256;
    for (int i = relblk * 256 + threadIdx.x; i < E; i += stride)
        atomicAdd(&cnt[dst[i]], 1);
}

// ---- component sums of x over nodes ----
template<int FIN, bool ISF32>
__device__ __forceinline__ void mean_body(
    const void* __restrict__ x, float* __restrict__ out, int N, int relblk, int nblk)
{
    const int stride = nblk * 256;
    float acc[FIN];
#pragma unroll
    for (int k = 0; k < FIN; ++k) acc[k] = 0.f;
    for (int n = relblk * 256 + threadIdx.x; n < N; n += stride) {
        if constexpr (FIN == 4 && ISF32) {
            const float4 xv = ((const float4*)x)[n];
            acc[0] += xv.x; acc[1] += xv.y; acc[2] += xv.z; acc[3] += xv.w;
        } else {
#pragma unroll
            for (int k = 0; k < FIN; ++k) acc[k] += ldf<ISF32>(x, n * FIN + k);
        }
    }
#pragma unroll
    for (int k = 0; k < FIN; ++k) {
        float v = wred(acc[k]);
        if ((threadIdx.x & 63) == 0)
            atomicAdd(&out[(blockIdx.x & 7) * 4 + k], v);
    }
}

// ---- phase 1: gine_a, gine_c, counts, x means ----
template<bool ISF32>
__device__ __forceinline__ void phase1_body(const Par p) {
    const int b = blockIdx.x;
    if (b < B_GA) {
        gine_body<3, 3, ISF32>(p.ei_a, p.ea_a, p.x_m, p.We_a, p.be_a,
                               p.Wm, p.bm, p.sums + SA_OFF, EA, b, B_GA);
    } else if (b < B_GA + B_GC) {
        gine_body<1, 4, ISF32>(p.ei_c, p.ea_c, p.x_o, p.We_c, p.be_c,
                               p.Wo, p.bo, p.sums + SC_OFF, EC, b - B_GA, B_GC);
    } else if (b < B_GA + B_GC + B_CT) {
        count_body(p.ei_tv + ET, p.cnt_m, ET, b - (B_GA + B_GC), B_CT);
    } else if (b < B_GA + B_GC + B_CT + B_CL) {
        count_body(p.ei_log + EL, p.cnt_o, EL, b - (B_GA + B_GC + B_CT), B_CL);
    } else if (b < B_GA + B_GC + B_CT + B_CL + B_MM) {
        mean_body<3, ISF32>(p.x_m, p.sums + XM_OFF, NM, b - (B_GA + B_GC + B_CT + B_CL), B_MM);
    } else {
        mean_body<4, ISF32>(p.x_o, p.sums + XO_OFF, NO, b - (B_GA + B_GC + B_CT + B_CL + B_MM), B_MO);
    }
}

__global__ __launch_bounds__(256) void phase1_kernel(const Par p) {
    if (*p.flag) phase1_body<true >(p);
    else         phase1_body<false>(p);
}

// ---- phase 2: SAGE weight scatter: w[src] += 1/max(cnt[dst],1) ----
__device__ __forceinline__ void wsc_body(
    const int* __restrict__ src, const int* __restrict__ dst,
    const int* __restrict__ cnt, float* __restrict__ w, int E, int relblk, int nblk)
{
    const int stride = nblk * 256;
    for (int i = relblk * 256 + threadIdx.x; i < E; i += stride) {
        const int s = src[i];
        const int c = cnt[dst[i]];
        const float inv = __builtin_amdgcn_rcpf((float)(c > 0 ? c : 1));
        atomicAdd(&w[s], inv);
    }
}

__global__ __launch_bounds__(256) void phase2_kernel(const Par p) {
    const int b = blockIdx.x;
    if (b < 512) wsc_body(p.ei_tv, p.ei_tv + ET, p.cnt_m, p.w_tv, ET, b, 512);
    else         wsc_body(p.ei_log, p.ei_log + EL, p.cnt_o, p.w_log, EL, b - 512, 256);
}

// ---- phase 3: weighted reduction over x_o: sum w*x (4) + sum w, for tv & log ----
template<bool ISF32>
__device__ __forceinline__ void phase3_body(const Par p) {
    const int stride = gridDim.x * 256;
    float twx[4] = {0, 0, 0, 0}, lwx[4] = {0, 0, 0, 0};
    float tsw = 0.f, lsw = 0.f;
    for (int n = blockIdx.x * 256 + threadIdx.x; n < NO; n += stride) {
        const float wt = p.w_tv[n];
        const float wl = p.w_log[n];
        float xv[4];
        if constexpr (ISF32) {
            const float4 t = ((const float4*)p.x_o)[n];
            xv[0] = t.x; xv[1] = t.y; xv[2] = t.z; xv[3] = t.w;
        } else {
#pragma unroll
            for (int k = 0; k < 4; ++k) xv[k] = ldf<ISF32>(p.x_o, n * 4 + k);
        }
#pragma unroll
        for (int k = 0; k < 4; ++k) {
            twx[k] = fmaf(wt, xv[k], twx[k]);
            lwx[k] = fmaf(wl, xv[k], lwx[k]);
        }
        tsw += wt; lsw += wl;
    }
    float* St = p.sums + TV_OFF + (blockIdx.x & 7) * 8;
    float* Sl = p.sums + LG_OFF + (blockIdx.x & 7) * 8;
#pragma unroll
    for (int k = 0; k < 4; ++k) {
        float v = wred(twx[k]);
        if ((threadIdx.x & 63) == 0) atomicAdd(&St[k], v);
        v = wred(lwx[k]);
        if ((threadIdx.x & 63) == 0) atomicAdd(&Sl[k], v);
    }
    float v = wred(tsw);
    if ((threadIdx.x & 63) == 0) atomicAdd(&St[4], v);
    v = wred(lsw);
    if ((threadIdx.x & 63) == 0) atomicAdd(&Sl[4], v);
}

__global__ __launch_bounds__(256) void phase3_kernel(const Par p) {
    if (*p.flag) phase3_body<true >(p);
    else         phase3_body<false>(p);
}

// ---- final: reconstruct means, five 128x128 mat-vecs, write 256 outputs ----
template<bool ISF32>
__device__ __forceinline__ void final_body(const Par p) {
    __shared__ float vtv[H], vmhm[H], va[H], vc[H], vlog[H], vmho[H];
    const float* S = p.sums;
    const int t = threadIdx.x;
    if (t < H) {
        float sa = 0.f, sc = 0.f;
        float xm[3] = {0, 0, 0}, xo[4] = {0, 0, 0, 0};
        float twx[4] = {0, 0, 0, 0}, lwx[4] = {0, 0, 0, 0};
        float tsw = 0.f, lsw = 0.f;
#pragma unroll
        for (int cp = 0; cp < 8; ++cp) {
            sa += S[SA_OFF + cp * H + t];
            sc += S[SC_OFF + cp * H + t];
#pragma unroll
            for (int k = 0; k < 3; ++k) xm[k] += S[XM_OFF + cp * 4 + k];
#pragma unroll
            for (int k = 0; k < 4; ++k) {
                xo[k]  += S[XO_OFF + cp * 4 + k];
                twx[k] += S[TV_OFF + cp * 8 + k];
                lwx[k] += S[LG_OFF + cp * 8 + k];
            }
            tsw += S[TV_OFF + cp * 8 + 4];
            lsw += S[LG_OFF + cp * 8 + 4];
        }
        // mean h_m = mean(x_m) @ Wm + bm
        float mhm = ldf<ISF32>(p.bm, t);
#pragma unroll
        for (int k = 0; k < 3; ++k)
            mhm = fmaf(xm[k] * (1.f / NM), ldf<ISF32>(p.Wm, k * H + t), mhm);
        // mean h_o = mean(x_o) @ Wo + bo
        float mho = ldf<ISF32>(p.bo, t);
#pragma unroll
        for (int k = 0; k < 4; ++k)
            mho = fmaf(xo[k] * (1.f / NO), ldf<ISF32>(p.Wo, k * H + t), mho);
        // mean sage agg = ((sum w*x)@Wo + (sum w)*bo) / Ndst
        float tv = tsw * ldf<ISF32>(p.bo, t);
        float lg = lsw * ldf<ISF32>(p.bo, t);
#pragma unroll
        for (int k = 0; k < 4; ++k) {
            tv = fmaf(twx[k], ldf<ISF32>(p.Wo, k * H + t), tv);
            lg = fmaf(lwx[k], ldf<ISF32>(p.Wo, k * H + t), lg);
        }
        vmhm[t] = mhm;
        vmho[t] = mho;
        vtv[t]  = tv * (1.f / NM);
        vlog[t] = lg * (1.f / NO);
        va[t] = sa * (1.f / NO) + mho;
        vc[t] = sc * (1.f / NO) + mho;
    }
    __syncthreads();
    float res; int oidx;
    if (t < H) {
        // g_m = mean_agg_tv @ Wl_tv + bl_tv + mean_h_m @ Wr_tv
        float acc = ldf<ISF32>(p.bl_tv, t);
        for (int k = 0; k < H; ++k) {
            acc = fmaf(vtv[k],  ldf<ISF32>(p.Wl_tv, k * H + t), acc);
            acc = fmaf(vmhm[k], ldf<ISF32>(p.Wr_tv, k * H + t), acc);
        }
        res = acc; oidx = t;
    } else {
        const int c = t - H;
        float acc = ldf<ISF32>(p.bn_a, c) + ldf<ISF32>(p.bn_c, c) + ldf<ISF32>(p.bl_log, c);
        for (int k = 0; k < H; ++k) {
            acc = fmaf(va[k],   ldf<ISF32>(p.Wn_a, k * H + c), acc);
            acc = fmaf(vc[k],   ldf<ISF32>(p.Wn_c, k * H + c), acc);
            acc = fmaf(vlog[k], ldf<ISF32>(p.Wl_log, k * H + c), acc);
            acc = fmaf(vmho[k], ldf<ISF32>(p.Wr_log, k * H + c), acc);
        }
        res = acc * (1.f / 3.f); oidx = H + c;
    }
    if constexpr (ISF32) ((float*)p.out)[oidx] = res;
    else                 ((bf16*)p.out)[oidx] = __float2bfloat16(res);
}

__global__ __launch_bounds__(256) void final_kernel(const Par p) {
    if (*p.flag) final_body<true >(p);
    else         final_body<false>(p);
}

extern "C" void kernel_launch(void* const* d_in, const int* in_sizes, int n_in,
                              void* d_out, int out_size, void* d_ws, size_t ws_size,
                              hipStream_t stream) {
    char* ws = (char*)d_ws;
    Par p;
    p.x_m   = d_in[0];  p.x_o   = d_in[1];
    p.ea_a  = d_in[2];  p.ea_c  = d_in[3];
    p.ei_a  = (const int*)d_in[4];
    p.ei_c  = (const int*)d_in[5];
    p.ei_tv = (const int*)d_in[6];
    p.ei_log= (const int*)d_in[7];
    p.Wm = d_in[8];  p.bm = d_in[9];  p.Wo = d_in[10]; p.bo = d_in[11];
    p.Wn_a = d_in[12]; p.bn_a = d_in[13]; p.We_a = d_in[14]; p.be_a = d_in[15];
    p.Wn_c = d_in[16]; p.bn_c = d_in[17]; p.We_c = d_in[18]; p.be_c = d_in[19];
    p.Wl_tv = d_in[20]; p.bl_tv = d_in[21]; p.Wr_tv = d_in[22];
    p.Wl_log = d_in[23]; p.bl_log = d_in[24]; p.Wr_log = d_in[25];

    // Workspace layout (bytes) — total ~1.23 MB:
    //   [0,        400000)  w_tv  float[NO]
    //   [400000,   800000)  w_log float[NO]
    //   [800000,   820000)  cnt_m int[NM]
    //   [820000,  1220000)  cnt_o int[NO]
    //   [1220000, 1228960)  sums  float[2240]
    //   [1228960, 1228964)  flag  int
    p.w_tv  = (float*)(ws);
    p.w_log = (float*)(ws + 400000);
    p.cnt_m = (int*)(ws + 800000);
    p.cnt_o = (int*)(ws + 820000);
    p.sums  = (float*)(ws + 1220000);
    int* flag = (int*)(ws + 1228960);
    p.flag  = flag;
    p.out   = d_out;

    // zero all accumulators + flag: bytes [0, 1228964) -> 307241 ints
    const int nzero = 307241;
    zero_kernel<<<(nzero + 255) / 256, 256, 0, stream>>>((int*)ws, nzero);

    // dtype probe on x_machine (first 15000 u16 — in-bounds under either dtype)
    detect_kernel<<<59, 256, 0, stream>>>((const uint16_t*)d_in[0], 15000, flag);

    phase1_kernel<<<P1_BLOCKS, 256, 0, stream>>>(p);
    phase2_kernel<<<768, 256, 0, stream>>>(p);
    phase3_kernel<<<256, 256, 0, stream>>>(p);
    final_kernel<<<1, 256, 0, stream>>>(p);
}